// Round 3
// baseline (1045.345 us; speedup 1.0000x reference)
//
#include <hip/hip_runtime.h>
#include <utility>
#include <cstddef>

#define SUBN 20
#define EN   2000
#define TN   50
#define HIDN 10
#define CHN  200     // SUBN*HIDN
#define BN   8
#define TD   5000
#define TP   5056    // 79*64 padded T
#define NOB  79
#define LAM  2.8853900817779268f   // 2*log2(e): tanh(x)=1-2/(2^(LAM*x)+1)

// workspace layout (float offsets)
#define OFF_CP  0                      // 20*2000 = 40000
#define OFF_G   40000                  // 200
#define OFF_SYN 40200                  // 8*20*5056 = 808960
#define OFF_U   849160                 // 8*200*5056 = 8089600
#define OFF_Y   8938760                // 8*200*5056 = 8089600

// ---------------- prep: C' = C_syn_e * exp(E_scale), g = exp(W_layer2) ----
__global__ __launch_bounds__(256) void k_prep(const float* __restrict__ Ce,
                                              const float* __restrict__ Es,
                                              const float* __restrict__ W2,
                                              float* __restrict__ Cp,
                                              float* __restrict__ g) {
    int idx = blockIdx.x * 256 + threadIdx.x;
    if (idx < SUBN * EN) {
        int e = idx % EN;
        Cp[idx] = Ce[idx] * __expf(Es[e]);
    } else if (idx < SUBN * EN + CHN) {
        g[idx - SUBN * EN] = __expf(W2[idx - SUBN * EN]);
    }
}

// ---------------- wave-wide sum via DPP (VALU pipe), result in lane 63 ----
__device__ __forceinline__ float wred(float x) {
    x += __int_as_float(__builtin_amdgcn_update_dpp(0, __float_as_int(x), 0x111, 0xF, 0xF, true)); // row_shr:1
    x += __int_as_float(__builtin_amdgcn_update_dpp(0, __float_as_int(x), 0x112, 0xF, 0xF, true)); // row_shr:2
    x += __int_as_float(__builtin_amdgcn_update_dpp(0, __float_as_int(x), 0x114, 0xF, 0xF, true)); // row_shr:4
    x += __int_as_float(__builtin_amdgcn_update_dpp(0, __float_as_int(x), 0x118, 0xF, 0xF, true)); // row_shr:8
    x += __int_as_float(__builtin_amdgcn_update_dpp(0, __float_as_int(x), 0x142, 0xF, 0xF, true)); // row_bcast:15
    x += __int_as_float(__builtin_amdgcn_update_dpp(0, __float_as_int(x), 0x143, 0xF, 0xF, true)); // row_bcast:31
    return x;
}

// ---------------- phase A: syn[b][s][t] = sum_e Se[b][t][e]*Cp[s][e] -------
// Lanes over e (lane owns e = 4*lane + 256k), 4 t-rows per wave (80 accs ->
// ~3 waves/SIMD). Se chunk double-buffered in regs; Cp 3-deep pipeline.
__global__ __launch_bounds__(256) void k_gemm(const float* __restrict__ Se,
                                              const float* __restrict__ Cp,
                                              float* __restrict__ syn) {
    const int tid  = threadIdx.x;
    const int lane = tid & 63;
    const int wave = tid >> 6;
    const int r0   = blockIdx.x * 16 + wave * 4;   // first of 4 rows (b*TD+t)
    const size_t rbase = (size_t)r0 * EN;
    const int le   = 4 * lane;
    const bool ok7 = (le < 208);                   // k=7 chunk covers e 1792..1999

    float acc[SUBN][4];
    #pragma unroll
    for (int s = 0; s < SUBN; ++s)
        #pragma unroll
        for (int t = 0; t < 4; ++t) acc[s][t] = 0.0f;

    float4 se_n[4];
    #pragma unroll
    for (int t = 0; t < 4; ++t)
        se_n[t] = *(const float4*)(Se + rbase + (size_t)t * EN + le);

    for (int k = 0; k < 8; ++k) {
        float4 se_c[4];
        #pragma unroll
        for (int t = 0; t < 4; ++t) se_c[t] = se_n[t];
        if (k == 7 && !ok7) {
            #pragma unroll
            for (int t = 0; t < 4; ++t) se_c[t] = make_float4(0.f, 0.f, 0.f, 0.f);
        }
        if (k < 7) {                               // prefetch chunk k+1
            int kn   = k + 1;
            int coff = 256 * kn + le;
            if (kn == 7 && !ok7) coff = 0;         // clamp OOB lanes
            #pragma unroll
            for (int t = 0; t < 4; ++t)
                se_n[t] = *(const float4*)(Se + rbase + (size_t)t * EN + coff);
        }
        const float* cp0 = Cp + 256 * k + le;      // tail lanes read g[]: finite, *0
        float4 cvq[3];
        #pragma unroll
        for (int j = 0; j < 3; ++j) cvq[j] = *(const float4*)(cp0 + j * EN);
        #pragma unroll
        for (int s = 0; s < SUBN; ++s) {
            float4 cv = cvq[s % 3];
            if (s + 3 < SUBN) cvq[s % 3] = *(const float4*)(cp0 + (s + 3) * EN);
            #pragma unroll
            for (int t = 0; t < 4; ++t) {
                acc[s][t] = fmaf(cv.x, se_c[t].x, acc[s][t]);
                acc[s][t] = fmaf(cv.y, se_c[t].y, acc[s][t]);
                acc[s][t] = fmaf(cv.z, se_c[t].z, acc[s][t]);
                acc[s][t] = fmaf(cv.w, se_c[t].w, acc[s][t]);
            }
        }
    }

    #pragma unroll
    for (int s = 0; s < SUBN; ++s)
        #pragma unroll
        for (int t = 0; t < 4; ++t) acc[s][t] = wred(acc[s][t]);

    if (lane == 63) {
        const int b  = r0 / TD;       // 4 rows never straddle batch (TD%4==0)
        const int tt = r0 - b * TD;
        float* sp = syn + (size_t)(b * SUBN) * TP + tt;
        #pragma unroll
        for (int s = 0; s < SUBN; ++s)
            *(float4*)(sp + (size_t)s * TP) =
                make_float4(acc[s][0], acc[s][1], acc[s][2], acc[s][3]);
    }
}

// ---------------- phase B: u = LAM*(b1 + conv(W1, syn)) -------------------
// One block per (b,s,h): 1600 blocks. FIR weights in 50 VGPRs; 7 outputs per
// thread (lane stride 7 words -> conflict-free LDS).
__global__ __launch_bounds__(256, 4) void k_conv(const float* __restrict__ syn,
                                                 const float* __restrict__ W1,
                                                 const float* __restrict__ b1,
                                                 float* __restrict__ u) {
    __shared__ __align__(16) float srow[52 + TP + 12];   // 5120 floats
    const int bs  = blockIdx.x / HIDN;   // b*20+s
    const int h   = blockIdx.x % HIDN;
    const int s   = bs % SUBN;
    const int tid = threadIdx.x;

    for (int i = tid; i < 13; i += 256) ((float4*)srow)[i] = make_float4(0,0,0,0);
    for (int i = tid; i < 3; i += 256)
        ((float4*)(srow + 52 + TP))[i] = make_float4(0,0,0,0);
    const float4* srcp = (const float4*)(syn + (size_t)bs * TP);
    for (int i = tid; i < TP / 4; i += 256) ((float4*)(srow + 52))[i] = srcp[i];

    const int c = s * HIDN + h;
    float wreg[TN];
    #pragma unroll
    for (int j = 0; j < TN; ++j) wreg[j] = LAM * W1[c * TN + j];
    const float bh = LAM * b1[c];
    __syncthreads();

    float* urow = u + (size_t)(bs * HIDN + h) * TP;
    for (int task = 0; task < 3; ++task) {
        int gidx = tid + task * 256;
        if (gidx >= 723) break;
        int t0 = gidx * 7;
        float a[7];
        #pragma unroll
        for (int m = 0; m < 7; ++m) a[m] = bh;
        #pragma unroll
        for (int kk = 0; kk < 56; ++kk) {
            int k = kk - 49;
            float xv = srow[52 + t0 + k];
            #pragma unroll
            for (int m = 0; m < 7; ++m) {
                int j = m - k;
                if (j >= 0 && j < TN) a[m] = fmaf(wreg[j], xv, a[m]);
            }
        }
        #pragma unroll
        for (int m = 0; m < 7; ++m) {
            int t = t0 + m;
            if (t < TP) urow[t] = a[m];
        }
    }
}

// ---------------- phase C: the recurrence ---------------------------------
// 16 lanes per (b,c) channel. 64-slot transposed-FIR ring (4 slots/lane) for
// far taps d=7..50; near taps d=1..6 replicated (pend ring 8). Far value for
// slot P+7 swizzle-broadcast at step P, consumed at step P+7 (7-step DS
// slack, 7 in flight). Weights pre-scaled by LAM; u arrives pre-scaled.
struct Rec {
    float wl[64];
    float rst[16];         // rst[m] = (lane16==m) ? 0 : 1
    float wn1, wn2, wn3, wn4, wn5, wn6;
    float acc0, acc1, acc2, acc3;
    float pend[8];
    float bv[8];
    float yv[8];
    float4 upipe[8];
    float4 cur;
    const float* urow;
    float* yrow8;
    int lane16;
    int tbase;
    bool m0, m1, m2, storer;
};

template<int P>
__device__ __forceinline__ void rec_step(Rec& S) {
    if constexpr ((P & 3) == 0) {
        constexpr int Q = (P >> 2) & 7;
        S.cur = S.upipe[Q];
        int tl = S.tbase + P + 32;
        if (tl > TP - 4) tl = TP - 4;
        S.upipe[Q] = *(const float4*)(&S.urow[tl]);
    }
    float uval;
    if constexpr ((P & 3) == 0) uval = S.cur.x;
    else if constexpr ((P & 3) == 1) uval = S.cur.y;
    else if constexpr ((P & 3) == 2) uval = S.cur.z;
    else uval = S.cur.w;

    float uc  = uval + S.bv[P & 7];        // far part joins off the chain
    float pre = S.pend[P & 7] + uc;        // chain: add,exp2,add,rcp,fma,fma
    float ex  = __builtin_amdgcn_exp2f(pre);
    float rc  = __builtin_amdgcn_rcpf(ex + 1.0f);
    float y   = __builtin_fmaf(-2.0f, rc, 1.0f);
    S.yv[P & 7] = y;

    S.acc0 = __builtin_fmaf(S.wl[( 64 - P) & 63], y, S.acc0);
    S.acc1 = __builtin_fmaf(S.wl[( 80 - P) & 63], y, S.acc1);
    S.acc2 = __builtin_fmaf(S.wl[( 96 - P) & 63], y, S.acc2);
    S.acc3 = __builtin_fmaf(S.wl[(112 - P) & 63], y, S.acc3);

    S.pend[(P + 6) & 7] = S.wn6 * y;
    S.pend[(P + 1) & 7] = __builtin_fmaf(S.wn1, y, S.pend[(P + 1) & 7]);
    S.pend[(P + 2) & 7] = __builtin_fmaf(S.wn2, y, S.pend[(P + 2) & 7]);
    S.pend[(P + 3) & 7] = __builtin_fmaf(S.wn3, y, S.pend[(P + 3) & 7]);
    S.pend[(P + 4) & 7] = __builtin_fmaf(S.wn4, y, S.pend[(P + 4) & 7]);
    S.pend[(P + 5) & 7] = __builtin_fmaf(S.wn5, y, S.pend[(P + 5) & 7]);

    // slot P+7 just got its last far tap (d=7 from y_P): broadcast now,
    // consume at step P+7. Reset owner's acc via 0/1-mask multiply.
    constexpr int SB  = (P + 7) & 63;
    constexpr int KB  = SB >> 4;
    constexpr int OWB = SB & 15;
    float av;
    if constexpr (KB == 0) av = S.acc0;
    else if constexpr (KB == 1) av = S.acc1;
    else if constexpr (KB == 2) av = S.acc2;
    else av = S.acc3;
    S.bv[(P + 7) & 7] = __int_as_float(
        __builtin_amdgcn_ds_swizzle(__float_as_int(av), (OWB << 5) | 0x10));
    float nv = av * S.rst[OWB];
    if constexpr (KB == 0) S.acc0 = nv;
    else if constexpr (KB == 1) S.acc1 = nv;
    else if constexpr (KB == 2) S.acc2 = nv;
    else S.acc3 = nv;

    if constexpr ((P & 7) == 7) {
        float a0 = S.m0 ? S.yv[1] : S.yv[0];
        float a1 = S.m0 ? S.yv[3] : S.yv[2];
        float a2 = S.m0 ? S.yv[5] : S.yv[4];
        float a3 = S.m0 ? S.yv[7] : S.yv[6];
        float b0 = S.m1 ? a1 : a0;
        float b1 = S.m1 ? a3 : a2;
        float sv = S.m2 ? b1 : b0;
        if (S.storer) S.yrow8[S.tbase + P - 7] = sv;
    }
}

template<int... Ps>
__device__ __forceinline__ void rec_steps(Rec& S, std::integer_sequence<int, Ps...>) {
    (rec_step<Ps>(S), ...);
}

__global__ __launch_bounds__(256) void k_rec(const float* __restrict__ u,
                                             const float* __restrict__ Wh,
                                             float* __restrict__ ybuf) {
    const int tid   = blockIdx.x * 256 + threadIdx.x;
    const int group = tid >> 4;          // 0..1599 == b*200 + c
    Rec S;
    S.lane16 = tid & 15;
    const int c = group % CHN;
    S.urow  = u    + (size_t)group * TP;
    S.yrow8 = ybuf + (size_t)group * TP + (S.lane16 & 7);
    S.m0 = (S.lane16 & 1) != 0;
    S.m1 = (S.lane16 & 2) != 0;
    S.m2 = (S.lane16 & 4) != 0;
    S.storer = S.lane16 < 8;
    const float* whc = Wh + c * TN;
    S.wn1 = LAM * whc[0]; S.wn2 = LAM * whc[1]; S.wn3 = LAM * whc[2];
    S.wn4 = LAM * whc[3]; S.wn5 = LAM * whc[4]; S.wn6 = LAM * whc[5];
    #pragma unroll
    for (int m = 0; m < 64; ++m) {
        int d = (S.lane16 + m) & 63;
        S.wl[m] = (d >= 7 && d <= TN) ? LAM * whc[d - 1] : 0.0f;
    }
    #pragma unroll
    for (int m = 0; m < 16; ++m) S.rst[m] = (S.lane16 == m) ? 0.0f : 1.0f;
    S.acc0 = S.acc1 = S.acc2 = S.acc3 = 0.f;
    #pragma unroll
    for (int i = 0; i < 8; ++i) { S.pend[i] = 0.f; S.bv[i] = 0.f; }
    #pragma unroll
    for (int q = 0; q < 8; ++q) S.upipe[q] = *(const float4*)(&S.urow[4 * q]);

    for (int ob = 0; ob < NOB; ++ob) {
        S.tbase = ob * 64;
        rec_steps(S, std::make_integer_sequence<int, 64>{});
    }
}

// ---------------- phase D: out[b][t] = Vo + sum_c g[c]*y[b][c][t] ----------
// 10-way channel split (20 ch each), atomicAdd into zeroed out. 400 blocks.
__global__ __launch_bounds__(256) void k_out(const float* __restrict__ ybuf,
                                             const float* __restrict__ g,
                                             const float* __restrict__ Vo,
                                             float* __restrict__ out) {
    const int cchunk = blockIdx.x % 10;
    const int tb     = blockIdx.x / 10;
    const int idx4   = tb * 256 + threadIdx.x;
    if (idx4 >= BN * TD / 4) return;
    const int t4 = idx4 * 4;
    const int b  = t4 / TD;
    const int tt = t4 - b * TD;
    const float* yp = ybuf + ((size_t)b * CHN + cchunk * 20) * TP + tt;
    const float* gp = g + cchunk * 20;
    float ax = 0.f, ay = 0.f, az = 0.f, aw = 0.f;
    if (cchunk == 0) { float v = Vo[0]; ax = ay = az = aw = v; }
    #pragma unroll
    for (int cc = 0; cc < 20; ++cc) {
        float4 y4 = *(const float4*)(yp + (size_t)cc * TP);
        float gc = gp[cc];
        ax = fmaf(gc, y4.x, ax);
        ay = fmaf(gc, y4.y, ay);
        az = fmaf(gc, y4.z, az);
        aw = fmaf(gc, y4.w, aw);
    }
    atomicAdd(out + t4 + 0, ax);
    atomicAdd(out + t4 + 1, ay);
    atomicAdd(out + t4 + 2, az);
    atomicAdd(out + t4 + 3, aw);
}

// ---------------------------------------------------------------------------
extern "C" void kernel_launch(void* const* d_in, const int* in_sizes, int n_in,
                              void* d_out, int out_size, void* d_ws, size_t ws_size,
                              hipStream_t stream) {
    const float* Se = (const float*)d_in[0];
    const float* Ce = (const float*)d_in[2];
    const float* Es = (const float*)d_in[4];
    const float* W1 = (const float*)d_in[6];
    const float* W2 = (const float*)d_in[7];
    const float* b1 = (const float*)d_in[8];
    const float* Wh = (const float*)d_in[9];
    const float* Vo = (const float*)d_in[11];
    float* ws  = (float*)d_ws;
    float* Cp  = ws + OFF_CP;
    float* g   = ws + OFF_G;
    float* syn = ws + OFF_SYN;
    float* u   = ws + OFF_U;
    float* yb  = ws + OFF_Y;
    float* out = (float*)d_out;

    hipMemsetAsync(d_out, 0, (size_t)out_size * sizeof(float), stream);
    hipLaunchKernelGGL(k_prep, dim3(158), dim3(256), 0, stream, Ce, Es, W2, Cp, g);
    hipLaunchKernelGGL(k_gemm, dim3(2500), dim3(256), 0, stream, Se, Cp, syn);
    hipLaunchKernelGGL(k_conv, dim3(BN * SUBN * HIDN), dim3(256), 0, stream, syn, W1, b1, u);
    hipLaunchKernelGGL(k_rec,  dim3(100), dim3(256), 0, stream, u, Wh, yb);
    hipLaunchKernelGGL(k_out,  dim3(400), dim3(256), 0, stream, yb, g, Vo, out);
}